// Round 1
// baseline (235.320 us; speedup 1.0000x reference)
//
#include <hip/hip_runtime.h>

// Problem constants (match reference)
constexpr int kB = 32;
constexpr int kC = 128;
constexpr int kT = 8192;
constexpr int kK = 33;                       // NUM_CPNTS
constexpr float kDT = 2.0f / (kK - 1);       // 0.0625
constexpr float kInvDT = (kK - 1) / 2.0f;    // 16.0

__device__ __forceinline__ float pwl_eval(float xv, const float* __restrict__ sl,
                                          const float* __restrict__ cb) {
    // fi = floor((x+1)/dt); ind1 = clamp(fi+1,0,K); ind2 = clamp(fi,0,K-1)
    float t = fmaf(xv, kInvDT, kInvDT);      // (x+1)*16 with single rounding
    int fi = (int)floorf(t);
    int i1 = fi + 1;
    i1 = i1 < 0 ? 0 : (i1 > kK ? kK : i1);
    int i2 = fi;
    i2 = i2 < 0 ? 0 : (i2 > kK - 1 ? kK - 1 : i2);
    float cp = fmaf((float)i2, kDT, -1.0f);  // left breakpoint
    return fmaf(xv - cp, sl[i1], cb[i2]);
}

__global__ __launch_bounds__(256) void pwl_kernel(const float* __restrict__ x,
                                                  const float* __restrict__ slopes,
                                                  const float* __restrict__ biases,
                                                  float* __restrict__ out) {
    __shared__ float sl[kK + 1];  // 34 slopes for this channel
    __shared__ float cb[kK];      // 33 cumulative biases

    const int bc = blockIdx.x;          // row index in [0, B*C)
    const int c = bc & (kC - 1);        // channel (C=128 pow2)
    const int tid = threadIdx.x;

    if (tid < kK + 1) sl[tid] = slopes[c * (kK + 1) + tid];
    __syncthreads();
    if (tid < kK) {
        // cb[j] = bias + dt * sum_{i=1..j} slopes[c,i]  (matches jnp.cumsum order)
        float acc = biases[c];
        for (int i = 1; i <= tid; ++i) acc += sl[i] * kDT;
        cb[tid] = acc;
    }
    __syncthreads();

    const float4* __restrict__ xin = reinterpret_cast<const float4*>(x) + (size_t)bc * (kT / 4);
    float4* __restrict__ o = reinterpret_cast<float4*>(out) + (size_t)bc * (kT / 4);

    constexpr int kVecPerRow = kT / 4;        // 2048
    constexpr int kIters = kVecPerRow / 256;  // 8

    #pragma unroll
    for (int k = 0; k < kIters; ++k) {
        float4 v = xin[tid + k * 256];
        float4 r;
        r.x = pwl_eval(v.x, sl, cb);
        r.y = pwl_eval(v.y, sl, cb);
        r.z = pwl_eval(v.z, sl, cb);
        r.w = pwl_eval(v.w, sl, cb);
        o[tid + k * 256] = r;
    }
}

extern "C" void kernel_launch(void* const* d_in, const int* in_sizes, int n_in,
                              void* d_out, int out_size, void* d_ws, size_t ws_size,
                              hipStream_t stream) {
    const float* x = (const float*)d_in[0];        // [B, C, T]
    const float* slopes = (const float*)d_in[1];   // [C, K+1]
    const float* biases = (const float*)d_in[2];   // [C]
    float* out = (float*)d_out;                    // [B, C, T]

    // One block per (b, c) row: 4096 blocks x 256 threads, 8 float4 per thread.
    pwl_kernel<<<dim3(kB * kC), dim3(256), 0, stream>>>(x, slopes, biases, out);
}

// Round 2
// 233.049 us; speedup vs baseline: 1.0097x; 1.0097x over previous
//
#include <hip/hip_runtime.h>

// Problem constants (match reference)
constexpr int kB = 32;
constexpr int kC = 128;
constexpr int kT = 8192;
constexpr int kK = 33;                       // NUM_CPNTS
constexpr float kDT = 2.0f / (kK - 1);       // 0.0625
constexpr float kInvDT = (kK - 1) / 2.0f;    // 16.0

// Fused lookup table: tab[u] = (slopes[min(u,33)], cumbias[clamp(u-1,0,32)])
// where u = clamp(floor((x+1)*16) + 1, 0, 34).
//   u=0     : x below first breakpoint  -> (slopes[0],  cumbias[0])
//   u=1..33 : interior                   -> (slopes[u],  cumbias[u-1])
//   u=34    : x above last breakpoint    -> (slopes[33], cumbias[32])
constexpr int kTab = kK + 2;  // 35

__device__ __forceinline__ float pwl_eval(float xv, const float2* __restrict__ tab) {
    float t = fmaf(xv, kInvDT, kInvDT);      // (x+1)*16, single rounding
    int fi = (int)floorf(t);
    int u = min(max(fi + 1, 0), kTab - 1);   // table index, v_med3-able
    int i2 = min(max(fi, 0), kK - 1);        // left-breakpoint index
    float cp = fmaf((float)i2, kDT, -1.0f);  // left breakpoint coordinate
    float2 p = tab[u];                       // ONE ds_read_b64 gather
    return fmaf(xv - cp, p.x, p.y);
}

__global__ __launch_bounds__(256) void pwl_kernel(const float* __restrict__ x,
                                                  const float* __restrict__ slopes,
                                                  const float* __restrict__ biases,
                                                  float* __restrict__ out) {
    __shared__ float sl[kK + 1];   // 34 raw slopes for this channel
    __shared__ float2 tab[kTab];   // 35 fused (slope, cumbias) entries

    const int bc = blockIdx.x;          // row index in [0, B*C)
    const int c = bc & (kC - 1);        // channel (C=128 pow2)
    const int tid = threadIdx.x;

    if (tid < kK + 1) sl[tid] = slopes[c * (kK + 1) + tid];
    __syncthreads();
    if (tid < kTab) {
        int su = min(tid, kK);                 // slope index
        int j = min(max(tid - 1, 0), kK - 1);  // cumbias index
        // cumbias[j] = bias + dt * sum_{i=1..j} slopes[i]  (matches jnp.cumsum)
        float acc = biases[c];
        for (int i = 1; i <= j; ++i) acc = fmaf(sl[i], kDT, acc);
        tab[tid] = make_float2(sl[su], acc);
    }
    __syncthreads();

    const float4* __restrict__ xin = reinterpret_cast<const float4*>(x) + (size_t)bc * (kT / 4);
    float4* __restrict__ o = reinterpret_cast<float4*>(out) + (size_t)bc * (kT / 4);

    constexpr int kIters = (kT / 4) / 256;  // 8 float4 per thread

    // Stage all global loads first: 8 loads in flight, hides HBM/LLC latency.
    float4 v[kIters];
    #pragma unroll
    for (int k = 0; k < kIters; ++k) v[k] = xin[tid + k * 256];

    // Consume: fully unrolled so the 32 ds_read_b64 gathers can overlap.
    #pragma unroll
    for (int k = 0; k < kIters; ++k) {
        float4 r;
        r.x = pwl_eval(v[k].x, tab);
        r.y = pwl_eval(v[k].y, tab);
        r.z = pwl_eval(v[k].z, tab);
        r.w = pwl_eval(v[k].w, tab);
        o[tid + k * 256] = r;
    }
}

extern "C" void kernel_launch(void* const* d_in, const int* in_sizes, int n_in,
                              void* d_out, int out_size, void* d_ws, size_t ws_size,
                              hipStream_t stream) {
    const float* x = (const float*)d_in[0];        // [B, C, T]
    const float* slopes = (const float*)d_in[1];   // [C, K+1]
    const float* biases = (const float*)d_in[2];   // [C]
    float* out = (float*)d_out;                    // [B, C, T]

    // One block per (b, c) row: 4096 blocks x 256 threads.
    pwl_kernel<<<dim3(kB * kC), dim3(256), 0, stream>>>(x, slopes, biases, out);
}